// Round 13
// baseline (63.800 us; speedup 1.0000x reference)
//
#include <hip/hip_runtime.h>

#define N_NODES 50000
#define N_EDGES 800000
#define DIN 256
#define DOUT 64
#define LN_EPS 1e-5f
#define NB 782        // ceil(N_NODES/64) buckets of 64 dsts
#define BCAP 2048     // bucket capacity (mean 1024, sd ~32)

typedef __attribute__((ext_vector_type(8))) short bfrag8;
typedef __attribute__((ext_vector_type(4))) float f32x4;

__device__ inline unsigned short f2bf(float f) {
    unsigned u = __builtin_bit_cast(unsigned, f);
    u += 0x7fffu + ((u >> 16) & 1u);          // round-to-nearest-even
    return (unsigned short)(u >> 16);
}
__device__ inline float bf2f(unsigned short b) {
    unsigned u = ((unsigned)b) << 16;
    return __builtin_bit_cast(float, u);
}

// ---------------- zero gcur ----------------
__global__ void zero_gcur_kernel(int* __restrict__ gcur) {
    int i = threadIdx.x;
    if (i < NB) gcur[i] = 0;
}

// ---------------- partition: bucket edges by dst/64 (coarse radix pass) ------
// 1024 thr x 16 edges = 16384 edges/block (49 blocks): doubles per-
// (block,bucket) run length (~21 edges = 84B) -> fewer partial-line scatters.
__global__ __launch_bounds__(1024) void partition_kernel(
    const int* __restrict__ ei, int* __restrict__ gcur, unsigned* __restrict__ bdata) {
    __shared__ int hist[NB];
    __shared__ int hbase[NB];
    const int tid = threadIdx.x;
    for (int c = tid; c < NB; c += 1024) hist[c] = 0;
    __syncthreads();
    const int chunk = blockIdx.x * 16384;
    unsigned u[16];
    int bk[16];
    int rk[16];
    #pragma unroll
    for (int i = 0; i < 16; ++i) {
        int e = chunk + i * 1024 + tid;
        if (e < N_EDGES) {
            int s = ei[e];
            int d = ei[N_EDGES + e];
            u[i] = (unsigned)s | ((unsigned)(d & 63) << 17);
            bk[i] = d >> 6;
            rk[i] = atomicAdd(&hist[bk[i]], 1);
        } else { bk[i] = -1; u[i] = 0; rk[i] = 0; }
    }
    __syncthreads();
    for (int c = tid; c < NB; c += 1024) {
        int n = hist[c];
        hbase[c] = n ? atomicAdd(&gcur[c], n) : 0;
    }
    __syncthreads();
    #pragma unroll
    for (int i = 0; i < 16; ++i) {
        if (bk[i] >= 0) {
            int off = hbase[bk[i]] + rk[i];
            if (off < BCAP) bdata[(size_t)bk[i] * BCAP + off] = u[i];
        }
    }
}

// ------ per-bucket counting sort by dst + dinv + per-node CSR bounds ---------
__global__ __launch_bounds__(512) void sort_dinv_kernel(
    unsigned* __restrict__ bdata, const int* __restrict__ gcur,
    float* __restrict__ dinv, int* __restrict__ nstart, int* __restrict__ nend) {
    __shared__ unsigned buf[BCAP];   // 8KB
    __shared__ int hist[64];
    __shared__ int pre[64];
    const int tid = threadIdx.x, b = blockIdx.x;
    if (tid < 64) hist[tid] = 0;
    __syncthreads();
    int cntb = gcur[b];
    if (cntb > BCAP) cntb = BCAP;
    unsigned* bd = bdata + (size_t)b * BCAP;
    unsigned v[4];
    int rk[4];
    #pragma unroll
    for (int j = 0; j < 4; ++j) {
        int i = tid + j * 512;
        if (i < cntb) {
            v[j] = bd[i];
            rk[j] = atomicAdd(&hist[v[j] >> 17], 1);
        } else { v[j] = 0; rk[j] = -1; }
    }
    __syncthreads();
    if (tid < 64) {                      // wave 0: exclusive scan of hist
        int n = hist[tid], s = n;
        #pragma unroll
        for (int d = 1; d < 64; d <<= 1) {
            int t = __shfl_up(s, d, 64);
            if (tid >= d) s += t;
        }
        pre[tid] = s - n;
        int node = b * 64 + tid;
        if (node < N_NODES) {
            dinv[node] = rsqrtf((float)(n + 1));   // +1 self loop
            nstart[node] = b * BCAP + (s - n);
            nend[node]   = b * BCAP + s;
        }
    }
    __syncthreads();
    #pragma unroll
    for (int j = 0; j < 4; ++j) {
        if (rk[j] >= 0)
            buf[pre[v[j] >> 17] + rk[j]] = v[j] & 0x1FFFF;   // src only
    }
    __syncthreads();
    #pragma unroll
    for (int j = 0; j < 4; ++j) {
        int i = tid + j * 512;
        if (i < cntb) bd[i] = buf[i];    // coalesced writeback
    }
}

// ------- MFMA GEMM: hs[n][d] = (sum_k xs[n][k] * W[d][k]) * dinv[n], bf16 ----
__global__ __launch_bounds__(512) void gemm_kernel(const float* __restrict__ xs,
                                                   const float* __restrict__ W,
                                                   const float* __restrict__ dinv,
                                                   unsigned short* __restrict__ hs) {
    __shared__ bfrag8 wg[64 * 32];   // 32KB bf16 W
    const int tid = threadIdx.x;
    #pragma unroll
    for (int i = 0; i < 4; ++i) {
        int gi = tid + i * 512;              // 0..2047
        int d = gi >> 5, g = gi & 31;
        const float* src = W + d * 256 + g * 8;
        f32x4 f0 = *(const f32x4*)src;
        f32x4 f1 = *(const f32x4*)(src + 4);
        union { unsigned short us[8]; bfrag8 v; } p;
        p.us[0] = f2bf(f0.x); p.us[1] = f2bf(f0.y);
        p.us[2] = f2bf(f0.z); p.us[3] = f2bf(f0.w);
        p.us[4] = f2bf(f1.x); p.us[5] = f2bf(f1.y);
        p.us[6] = f2bf(f1.z); p.us[7] = f2bf(f1.w);
        wg[d * 32 + (g ^ (d & 7))] = p.v;
    }
    __syncthreads();

    const int lane = tid & 63, wv = tid >> 6;
    const int n0 = (blockIdx.x * 8 + wv) * 16;
    int arow = n0 + (lane & 15);
    if (arow >= N_NODES) arow = N_NODES - 1;          // clamp (loads only)
    const float* xrow = xs + (size_t)arow * DIN + (lane >> 4) * 8;

    f32x4 acc[4] = {{0.f, 0.f, 0.f, 0.f}, {0.f, 0.f, 0.f, 0.f},
                    {0.f, 0.f, 0.f, 0.f}, {0.f, 0.f, 0.f, 0.f}};
    const int swz = lane & 7;
    #pragma unroll
    for (int s = 0; s < 8; ++s) {
        f32x4 xa = *(const f32x4*)(xrow + s * 32);
        f32x4 xb = *(const f32x4*)(xrow + s * 32 + 4);
        union { unsigned short us[8]; bfrag8 v; } a;
        a.us[0] = f2bf(xa.x); a.us[1] = f2bf(xa.y);
        a.us[2] = f2bf(xa.z); a.us[3] = f2bf(xa.w);
        a.us[4] = f2bf(xb.x); a.us[5] = f2bf(xb.y);
        a.us[6] = f2bf(xb.z); a.us[7] = f2bf(xb.w);
        int g = s * 4 + (lane >> 4);
        #pragma unroll
        for (int t = 0; t < 4; ++t) {
            bfrag8 b = wg[(t * 16 + (lane & 15)) * 32 + (g ^ swz)];
            acc[t] = __builtin_amdgcn_mfma_f32_16x16x32_bf16(a.v, b, acc[t], 0, 0, 0);
        }
    }
    // C/D: col = lane&15, row = (lane>>4)*4 + r ; scale by dinv[row] on store
    #pragma unroll
    for (int t = 0; t < 4; ++t) {
        #pragma unroll
        for (int r = 0; r < 4; ++r) {
            int row = n0 + (lane >> 4) * 4 + r;
            if (row < N_NODES) {
                float dr = dinv[row];
                hs[(size_t)row * DOUT + t * 16 + (lane & 15)] = f2bf(acc[t][r] * dr);
            }
        }
    }
}

// -------- CSR aggregate: 8 nodes/wave, 8 lanes/node, uint4 (8 bf16)/lane -----
// Each hs-row load instruction fetches 8 independent edge rows (8x128B);
// x8 unroll = 64 rows in flight per wave. No branches/LDS atomics in hot loop.
__global__ __launch_bounds__(256) void csr_agg_ln_kernel(
    const unsigned* __restrict__ csr, const int* __restrict__ nstart,
    const int* __restrict__ nend, const unsigned short* __restrict__ hs,
    const float* __restrict__ dinv, const float* __restrict__ bias,
    const float* __restrict__ gamma, const float* __restrict__ beta,
    float* __restrict__ out) {
    const int tid = threadIdx.x, lane = tid & 63, wv = tid >> 6;
    const int q = lane >> 3;          // which of the wave's 8 nodes
    const int fl = lane & 7;          // feature octet (8 feats, 16B) within node
    const int node = (blockIdx.x * 4 + wv) * 8 + q;
    if (node >= N_NODES) return;
    const int c0 = nstart[node];
    const int deg = nend[node] - c0;
    const int cmax = deg > 0 ? deg - 1 : 0;

    // self loop (hs pre-scaled by dinv[src])
    float a0, a1, a2, a3, a4, a5, a6, a7;
    {
        uint4 sv = *(const uint4*)(hs + (size_t)node * DOUT + fl * 8);
        a0 = bf2f((unsigned short)(sv.x & 0xFFFFu));
        a1 = bf2f((unsigned short)(sv.x >> 16));
        a2 = bf2f((unsigned short)(sv.y & 0xFFFFu));
        a3 = bf2f((unsigned short)(sv.y >> 16));
        a4 = bf2f((unsigned short)(sv.z & 0xFFFFu));
        a5 = bf2f((unsigned short)(sv.z >> 16));
        a6 = bf2f((unsigned short)(sv.w & 0xFFFFu));
        a7 = bf2f((unsigned short)(sv.w >> 16));
    }
    int maxd = deg;
    maxd = max(maxd, __shfl_xor(maxd, 8, 64));
    maxd = max(maxd, __shfl_xor(maxd, 16, 64));
    maxd = max(maxd, __shfl_xor(maxd, 32, 64));

    for (int j = 0; j < maxd; j += 8) {
        unsigned uu[8];
        #pragma unroll
        for (int k = 0; k < 8; ++k) {
            int jc = j + k; jc = jc < cmax ? jc : cmax;   // clamp, unconditional
            uu[k] = csr[c0 + jc];
        }
        uint4 hv[8];
        #pragma unroll
        for (int k = 0; k < 8; ++k) {
            unsigned src = uu[k];
            if (src > (unsigned)(N_NODES - 1)) src = N_NODES - 1;
            hv[k] = *(const uint4*)(hs + (size_t)src * DOUT + fl * 8);
        }
        #pragma unroll
        for (int k = 0; k < 8; ++k) {
            bool valid = (j + k) < deg;
            unsigned x = valid ? hv[k].x : 0u;   // cndmask, no branch
            unsigned y = valid ? hv[k].y : 0u;
            unsigned z = valid ? hv[k].z : 0u;
            unsigned w = valid ? hv[k].w : 0u;
            a0 += bf2f((unsigned short)(x & 0xFFFFu));
            a1 += bf2f((unsigned short)(x >> 16));
            a2 += bf2f((unsigned short)(y & 0xFFFFu));
            a3 += bf2f((unsigned short)(y >> 16));
            a4 += bf2f((unsigned short)(z & 0xFFFFu));
            a5 += bf2f((unsigned short)(z >> 16));
            a6 += bf2f((unsigned short)(w & 0xFFFFu));
            a7 += bf2f((unsigned short)(w >> 16));
        }
    }
    float di = dinv[node];
    float4 b40  = ((const float4*)bias)[fl * 2];
    float4 b41  = ((const float4*)bias)[fl * 2 + 1];
    float4 g40  = ((const float4*)gamma)[fl * 2];
    float4 g41  = ((const float4*)gamma)[fl * 2 + 1];
    float4 be40 = ((const float4*)beta)[fl * 2];
    float4 be41 = ((const float4*)beta)[fl * 2 + 1];
    a0 = a0 * di + b40.x; a1 = a1 * di + b40.y;
    a2 = a2 * di + b40.z; a3 = a3 * di + b40.w;
    a4 = a4 * di + b41.x; a5 = a5 * di + b41.y;
    a6 = a6 * di + b41.z; a7 = a7 * di + b41.w;
    // LayerNorm over 64 features = 8-lane group x 8 per lane
    float sum = ((a0 + a1) + (a2 + a3)) + ((a4 + a5) + (a6 + a7));
    #pragma unroll
    for (int d = 1; d < 8; d <<= 1) sum += __shfl_xor(sum, d, 64);
    float mu = sum * (1.0f / 64.0f);
    float d0 = a0 - mu, d1 = a1 - mu, d2 = a2 - mu, d3 = a3 - mu;
    float d4 = a4 - mu, d5 = a5 - mu, d6 = a6 - mu, d7 = a7 - mu;
    float vs = ((d0 * d0 + d1 * d1) + (d2 * d2 + d3 * d3))
             + ((d4 * d4 + d5 * d5) + (d6 * d6 + d7 * d7));
    #pragma unroll
    for (int d = 1; d < 8; d <<= 1) vs += __shfl_xor(vs, d, 64);
    float var = vs * (1.0f / 64.0f);
    float rinv = rsqrtf(var + LN_EPS);
    float4 o0, o1;
    o0.x = d0 * rinv * g40.x + be40.x;
    o0.y = d1 * rinv * g40.y + be40.y;
    o0.z = d2 * rinv * g40.z + be40.z;
    o0.w = d3 * rinv * g40.w + be40.w;
    o1.x = d4 * rinv * g41.x + be41.x;
    o1.y = d5 * rinv * g41.y + be41.y;
    o1.z = d6 * rinv * g41.z + be41.z;
    o1.w = d7 * rinv * g41.w + be41.w;
    float4* op = (float4*)(out + (size_t)node * DOUT + fl * 8);
    op[0] = o0;
    op[1] = o1;
}

extern "C" void kernel_launch(void* const* d_in, const int* in_sizes, int n_in,
                              void* d_out, int out_size, void* d_ws, size_t ws_size,
                              hipStream_t stream) {
    const float* xs    = (const float*)d_in[0];
    const int*   ei    = (const int*)d_in[1];
    const float* W     = (const float*)d_in[2];
    const float* bias  = (const float*)d_in[3];
    const float* gamma = (const float*)d_in[4];
    const float* beta  = (const float*)d_in[5];
    float* out = (float*)d_out;

    char* base = (char*)d_ws;
    auto align_up = [](size_t x) { return (x + 255) & ~(size_t)255; };
    size_t o = 0;
    int* gcur   = (int*)(base + o);      o = align_up(o + (size_t)NB * 4);
    float* dinv = (float*)(base + o);    o = align_up(o + (size_t)N_NODES * 4);
    unsigned* bdata = (unsigned*)(base + o);           // becomes sorted csr
    o = align_up(o + (size_t)NB * BCAP * 4);
    unsigned short* hs = (unsigned short*)(base + o);
    o = align_up(o + (size_t)N_NODES * DOUT * 2);
    int* nstart = (int*)(base + o);      o = align_up(o + (size_t)N_NODES * 4);
    int* nend   = (int*)(base + o);      o = align_up(o + (size_t)N_NODES * 4);
    (void)ws_size; (void)in_sizes; (void)n_in; (void)out_size;

    zero_gcur_kernel<<<1, 1024, 0, stream>>>(gcur);
    partition_kernel<<<(N_EDGES + 16383) / 16384, 1024, 0, stream>>>(ei, gcur, bdata);
    sort_dinv_kernel<<<NB, 512, 0, stream>>>(bdata, gcur, dinv, nstart, nend);
    gemm_kernel<<<(N_NODES + 127) / 128, 512, 0, stream>>>(xs, W, dinv, hs);
    csr_agg_ln_kernel<<<(N_NODES + 31) / 32, 256, 0, stream>>>(
        bdata, nstart, nend, hs, dinv, bias, gamma, beta, out);
}

// Round 14
// 63.366 us; speedup vs baseline: 1.0068x; 1.0068x over previous
//
#include <hip/hip_runtime.h>

#define N_NODES 50000
#define N_EDGES 800000
#define DIN 256
#define DOUT 64
#define LN_EPS 1e-5f
#define NB 782        // ceil(N_NODES/64) buckets of 64 dsts
#define BCAP 2048     // bucket capacity (mean 1024, sd ~32)

typedef __attribute__((ext_vector_type(8))) short bfrag8;
typedef __attribute__((ext_vector_type(4))) float f32x4;

__device__ inline unsigned short f2bf(float f) {
    unsigned u = __builtin_bit_cast(unsigned, f);
    u += 0x7fffu + ((u >> 16) & 1u);          // round-to-nearest-even
    return (unsigned short)(u >> 16);
}
__device__ inline float bf2f(unsigned short b) {
    unsigned u = ((unsigned)b) << 16;
    return __builtin_bit_cast(float, u);
}

// ---------------- zero gcur ----------------
__global__ void zero_gcur_kernel(int* __restrict__ gcur) {
    int i = threadIdx.x;
    if (i < NB) gcur[i] = 0;
}

// ---------------- partition: bucket edges by dst/64 (coarse radix pass) ------
__global__ __launch_bounds__(512) void partition_kernel(
    const int* __restrict__ ei, int* __restrict__ gcur, unsigned* __restrict__ bdata) {
    __shared__ int hist[NB];
    __shared__ int hbase[NB];
    const int tid = threadIdx.x;
    for (int c = tid; c < NB; c += 512) hist[c] = 0;
    __syncthreads();
    const int chunk = blockIdx.x * 8192;
    unsigned u[16];
    int bk[16];
    int rk[16];
    #pragma unroll
    for (int i = 0; i < 16; ++i) {
        int e = chunk + i * 512 + tid;
        if (e < N_EDGES) {
            int s = ei[e];
            int d = ei[N_EDGES + e];
            u[i] = (unsigned)s | ((unsigned)(d & 63) << 17);
            bk[i] = d >> 6;
            rk[i] = atomicAdd(&hist[bk[i]], 1);
        } else { bk[i] = -1; u[i] = 0; rk[i] = 0; }
    }
    __syncthreads();
    for (int c = tid; c < NB; c += 512) {
        int n = hist[c];
        hbase[c] = n ? atomicAdd(&gcur[c], n) : 0;
    }
    __syncthreads();
    #pragma unroll
    for (int i = 0; i < 16; ++i) {
        if (bk[i] >= 0) {
            int off = hbase[bk[i]] + rk[i];
            if (off < BCAP) bdata[(size_t)bk[i] * BCAP + off] = u[i];
        }
    }
}

// ------ per-bucket counting sort by dst + dinv + per-node CSR bounds ---------
__global__ __launch_bounds__(512) void sort_dinv_kernel(
    unsigned* __restrict__ bdata, const int* __restrict__ gcur,
    float* __restrict__ dinv, int* __restrict__ nstart, int* __restrict__ nend) {
    __shared__ unsigned buf[BCAP];   // 8KB
    __shared__ int hist[64];
    __shared__ int pre[64];
    const int tid = threadIdx.x, b = blockIdx.x;
    if (tid < 64) hist[tid] = 0;
    __syncthreads();
    int cntb = gcur[b];
    if (cntb > BCAP) cntb = BCAP;
    unsigned* bd = bdata + (size_t)b * BCAP;
    unsigned v[4];
    int rk[4];
    #pragma unroll
    for (int j = 0; j < 4; ++j) {
        int i = tid + j * 512;
        if (i < cntb) {
            v[j] = bd[i];
            rk[j] = atomicAdd(&hist[v[j] >> 17], 1);
        } else { v[j] = 0; rk[j] = -1; }
    }
    __syncthreads();
    if (tid < 64) {                      // wave 0: exclusive scan of hist
        int n = hist[tid], s = n;
        #pragma unroll
        for (int d = 1; d < 64; d <<= 1) {
            int t = __shfl_up(s, d, 64);
            if (tid >= d) s += t;
        }
        pre[tid] = s - n;
        int node = b * 64 + tid;
        if (node < N_NODES) {
            dinv[node] = rsqrtf((float)(n + 1));   // +1 self loop
            nstart[node] = b * BCAP + (s - n);
            nend[node]   = b * BCAP + s;
        }
    }
    __syncthreads();
    #pragma unroll
    for (int j = 0; j < 4; ++j) {
        if (rk[j] >= 0)
            buf[pre[v[j] >> 17] + rk[j]] = v[j] & 0x1FFFF;   // src only
    }
    __syncthreads();
    #pragma unroll
    for (int j = 0; j < 4; ++j) {
        int i = tid + j * 512;
        if (i < cntb) bd[i] = buf[i];    // coalesced writeback
    }
}

// ------- MFMA GEMM: hs[n][d] = (sum_k xs[n][k] * W[d][k]) * dinv[n], bf16 ----
__global__ __launch_bounds__(512) void gemm_kernel(const float* __restrict__ xs,
                                                   const float* __restrict__ W,
                                                   const float* __restrict__ dinv,
                                                   unsigned short* __restrict__ hs) {
    __shared__ bfrag8 wg[64 * 32];   // 32KB bf16 W
    const int tid = threadIdx.x;
    #pragma unroll
    for (int i = 0; i < 4; ++i) {
        int gi = tid + i * 512;              // 0..2047
        int d = gi >> 5, g = gi & 31;
        const float* src = W + d * 256 + g * 8;
        f32x4 f0 = *(const f32x4*)src;
        f32x4 f1 = *(const f32x4*)(src + 4);
        union { unsigned short us[8]; bfrag8 v; } p;
        p.us[0] = f2bf(f0.x); p.us[1] = f2bf(f0.y);
        p.us[2] = f2bf(f0.z); p.us[3] = f2bf(f0.w);
        p.us[4] = f2bf(f1.x); p.us[5] = f2bf(f1.y);
        p.us[6] = f2bf(f1.z); p.us[7] = f2bf(f1.w);
        wg[d * 32 + (g ^ (d & 7))] = p.v;
    }
    __syncthreads();

    const int lane = tid & 63, wv = tid >> 6;
    const int n0 = (blockIdx.x * 8 + wv) * 16;
    int arow = n0 + (lane & 15);
    if (arow >= N_NODES) arow = N_NODES - 1;          // clamp (loads only)
    const float* xrow = xs + (size_t)arow * DIN + (lane >> 4) * 8;

    f32x4 acc[4] = {{0.f, 0.f, 0.f, 0.f}, {0.f, 0.f, 0.f, 0.f},
                    {0.f, 0.f, 0.f, 0.f}, {0.f, 0.f, 0.f, 0.f}};
    const int swz = lane & 7;
    #pragma unroll
    for (int s = 0; s < 8; ++s) {
        f32x4 xa = *(const f32x4*)(xrow + s * 32);
        f32x4 xb = *(const f32x4*)(xrow + s * 32 + 4);
        union { unsigned short us[8]; bfrag8 v; } a;
        a.us[0] = f2bf(xa.x); a.us[1] = f2bf(xa.y);
        a.us[2] = f2bf(xa.z); a.us[3] = f2bf(xa.w);
        a.us[4] = f2bf(xb.x); a.us[5] = f2bf(xb.y);
        a.us[6] = f2bf(xb.z); a.us[7] = f2bf(xb.w);
        int g = s * 4 + (lane >> 4);
        #pragma unroll
        for (int t = 0; t < 4; ++t) {
            bfrag8 b = wg[(t * 16 + (lane & 15)) * 32 + (g ^ swz)];
            acc[t] = __builtin_amdgcn_mfma_f32_16x16x32_bf16(a.v, b, acc[t], 0, 0, 0);
        }
    }
    // C/D: col = lane&15, row = (lane>>4)*4 + r ; scale by dinv[row] on store
    #pragma unroll
    for (int t = 0; t < 4; ++t) {
        #pragma unroll
        for (int r = 0; r < 4; ++r) {
            int row = n0 + (lane >> 4) * 4 + r;
            if (row < N_NODES) {
                float dr = dinv[row];
                hs[(size_t)row * DOUT + t * 16 + (lane & 15)] = f2bf(acc[t][r] * dr);
            }
        }
    }
}

// -------- CSR aggregate: 4 nodes/wave, 16 lanes/node, uint2 (4 bf16)/lane ----
// 16-deep unrolled edge batches (was 8): per-wave iterations for mean maxd~21
// drop 3 -> 2; clamped extra slots re-read the same L1-resident row.
__global__ __launch_bounds__(256) void csr_agg_ln_kernel(
    const unsigned* __restrict__ csr, const int* __restrict__ nstart,
    const int* __restrict__ nend, const unsigned short* __restrict__ hs,
    const float* __restrict__ dinv, const float* __restrict__ bias,
    const float* __restrict__ gamma, const float* __restrict__ beta,
    float* __restrict__ out) {
    const int tid = threadIdx.x, lane = tid & 63, wv = tid >> 6;
    const int q = lane >> 4;          // which of the wave's 4 nodes
    const int fl = lane & 15;         // feature group (4 feats) within node
    const int node = (blockIdx.x * 4 + wv) * 4 + q;
    if (node >= N_NODES) return;
    const int c0 = nstart[node];
    const int deg = nend[node] - c0;
    const int cmax = deg > 0 ? deg - 1 : 0;

    // self loop (hs pre-scaled by dinv[src])
    uint2 sv = *(const uint2*)(hs + (size_t)node * DOUT + fl * 4);
    float a0 = bf2f((unsigned short)(sv.x & 0xFFFFu));
    float a1 = bf2f((unsigned short)(sv.x >> 16));
    float a2 = bf2f((unsigned short)(sv.y & 0xFFFFu));
    float a3 = bf2f((unsigned short)(sv.y >> 16));

    int maxd = deg;
    maxd = max(maxd, __shfl_xor(maxd, 16, 64));
    maxd = max(maxd, __shfl_xor(maxd, 32, 64));

    for (int j = 0; j < maxd; j += 16) {
        unsigned uu[16];
        #pragma unroll
        for (int k = 0; k < 16; ++k) {
            int jc = j + k; jc = jc < cmax ? jc : cmax;   // clamp, unconditional
            uu[k] = csr[c0 + jc];
        }
        uint2 hv[16];
        #pragma unroll
        for (int k = 0; k < 16; ++k) {
            unsigned src = uu[k];
            if (src > (unsigned)(N_NODES - 1)) src = N_NODES - 1;
            hv[k] = *(const uint2*)(hs + (size_t)src * DOUT + fl * 4);
        }
        #pragma unroll
        for (int k = 0; k < 16; ++k) {
            bool valid = (j + k) < deg;
            unsigned x = valid ? hv[k].x : 0u;   // cndmask, no branch
            unsigned y = valid ? hv[k].y : 0u;
            a0 += bf2f((unsigned short)(x & 0xFFFFu));
            a1 += bf2f((unsigned short)(x >> 16));
            a2 += bf2f((unsigned short)(y & 0xFFFFu));
            a3 += bf2f((unsigned short)(y >> 16));
        }
    }
    float di = dinv[node];
    float4 b4  = ((const float4*)bias)[fl];
    float4 g4  = ((const float4*)gamma)[fl];
    float4 be4 = ((const float4*)beta)[fl];
    a0 = a0 * di + b4.x;
    a1 = a1 * di + b4.y;
    a2 = a2 * di + b4.z;
    a3 = a3 * di + b4.w;
    // LayerNorm over 64 features = 16-lane group x 4 per lane
    float sum = (a0 + a1) + (a2 + a3);
    #pragma unroll
    for (int d = 1; d < 16; d <<= 1) sum += __shfl_xor(sum, d, 64);
    float mu = sum * (1.0f / 64.0f);
    float d0 = a0 - mu, d1 = a1 - mu, d2 = a2 - mu, d3 = a3 - mu;
    float vs = (d0 * d0 + d1 * d1) + (d2 * d2 + d3 * d3);
    #pragma unroll
    for (int d = 1; d < 16; d <<= 1) vs += __shfl_xor(vs, d, 64);
    float var = vs * (1.0f / 64.0f);
    float rinv = rsqrtf(var + LN_EPS);
    float4 ov;
    ov.x = d0 * rinv * g4.x + be4.x;
    ov.y = d1 * rinv * g4.y + be4.y;
    ov.z = d2 * rinv * g4.z + be4.z;
    ov.w = d3 * rinv * g4.w + be4.w;
    *(float4*)(out + (size_t)node * DOUT + fl * 4) = ov;
}

extern "C" void kernel_launch(void* const* d_in, const int* in_sizes, int n_in,
                              void* d_out, int out_size, void* d_ws, size_t ws_size,
                              hipStream_t stream) {
    const float* xs    = (const float*)d_in[0];
    const int*   ei    = (const int*)d_in[1];
    const float* W     = (const float*)d_in[2];
    const float* bias  = (const float*)d_in[3];
    const float* gamma = (const float*)d_in[4];
    const float* beta  = (const float*)d_in[5];
    float* out = (float*)d_out;

    char* base = (char*)d_ws;
    auto align_up = [](size_t x) { return (x + 255) & ~(size_t)255; };
    size_t o = 0;
    int* gcur   = (int*)(base + o);      o = align_up(o + (size_t)NB * 4);
    float* dinv = (float*)(base + o);    o = align_up(o + (size_t)N_NODES * 4);
    unsigned* bdata = (unsigned*)(base + o);           // becomes sorted csr
    o = align_up(o + (size_t)NB * BCAP * 4);
    unsigned short* hs = (unsigned short*)(base + o);
    o = align_up(o + (size_t)N_NODES * DOUT * 2);
    int* nstart = (int*)(base + o);      o = align_up(o + (size_t)N_NODES * 4);
    int* nend   = (int*)(base + o);      o = align_up(o + (size_t)N_NODES * 4);
    (void)ws_size; (void)in_sizes; (void)n_in; (void)out_size;

    zero_gcur_kernel<<<1, 1024, 0, stream>>>(gcur);
    partition_kernel<<<(N_EDGES + 8191) / 8192, 512, 0, stream>>>(ei, gcur, bdata);
    sort_dinv_kernel<<<NB, 512, 0, stream>>>(bdata, gcur, dinv, nstart, nend);
    gemm_kernel<<<(N_NODES + 127) / 128, 512, 0, stream>>>(xs, W, dinv, hs);
    csr_agg_ln_kernel<<<(N_NODES + 15) / 16, 256, 0, stream>>>(
        bdata, nstart, nend, hs, dinv, bias, gamma, beta, out);
}

// Round 15
// 61.232 us; speedup vs baseline: 1.0419x; 1.0348x over previous
//
#include <hip/hip_runtime.h>

#define N_NODES 50000
#define N_EDGES 800000
#define DIN 256
#define DOUT 64
#define LN_EPS 1e-5f
#define NB 782        // ceil(N_NODES/64) buckets of 64 dsts
#define BCAP 2048     // bucket capacity (mean 1024, sd ~32)
#define EPB 2048      // partition edges/block -> 391 blocks (CU coverage)

typedef __attribute__((ext_vector_type(8))) short bfrag8;
typedef __attribute__((ext_vector_type(4))) float f32x4;

__device__ inline unsigned short f2bf(float f) {
    unsigned u = __builtin_bit_cast(unsigned, f);
    u += 0x7fffu + ((u >> 16) & 1u);          // round-to-nearest-even
    return (unsigned short)(u >> 16);
}
__device__ inline float bf2f(unsigned short b) {
    unsigned u = ((unsigned)b) << 16;
    return __builtin_bit_cast(float, u);
}

// ---------------- zero gcur ----------------
__global__ void zero_gcur_kernel(int* __restrict__ gcur) {
    int i = blockIdx.x * 256 + threadIdx.x;
    if (i < NB) gcur[i] = 0;
}

// ---------------- partition: bucket edges by dst/64 (coarse radix pass) ------
// 391 blocks x 2048 edges (4/thread): full CU coverage (was 98 blocks = 38%).
__global__ __launch_bounds__(512) void partition_kernel(
    const int* __restrict__ ei, int* __restrict__ gcur, unsigned* __restrict__ bdata) {
    __shared__ int hist[NB];
    __shared__ int hbase[NB];
    const int tid = threadIdx.x;
    for (int c = tid; c < NB; c += 512) hist[c] = 0;
    __syncthreads();
    const int chunk = blockIdx.x * EPB;
    unsigned u[4];
    int bk[4];
    int rk[4];
    #pragma unroll
    for (int i = 0; i < 4; ++i) {
        int e = chunk + i * 512 + tid;
        if (e < N_EDGES) {
            int s = ei[e];
            int d = ei[N_EDGES + e];
            u[i] = (unsigned)s | ((unsigned)(d & 63) << 17);
            bk[i] = d >> 6;
            rk[i] = atomicAdd(&hist[bk[i]], 1);
        } else { bk[i] = -1; u[i] = 0; rk[i] = 0; }
    }
    __syncthreads();
    for (int c = tid; c < NB; c += 512) {
        int n = hist[c];
        hbase[c] = n ? atomicAdd(&gcur[c], n) : 0;
    }
    __syncthreads();
    #pragma unroll
    for (int i = 0; i < 4; ++i) {
        if (bk[i] >= 0) {
            int off = hbase[bk[i]] + rk[i];
            if (off < BCAP) bdata[(size_t)bk[i] * BCAP + off] = u[i];
        }
    }
}

// ------ per-bucket counting sort by dst + dinv + per-node CSR bounds ---------
__global__ __launch_bounds__(512) void sort_dinv_kernel(
    unsigned* __restrict__ bdata, const int* __restrict__ gcur,
    float* __restrict__ dinv, int* __restrict__ nstart, int* __restrict__ nend) {
    __shared__ unsigned buf[BCAP];   // 8KB
    __shared__ int hist[64];
    __shared__ int pre[64];
    const int tid = threadIdx.x, b = blockIdx.x;
    if (tid < 64) hist[tid] = 0;
    __syncthreads();
    int cntb = gcur[b];
    if (cntb > BCAP) cntb = BCAP;
    unsigned* bd = bdata + (size_t)b * BCAP;
    unsigned v[4];
    int rk[4];
    #pragma unroll
    for (int j = 0; j < 4; ++j) {
        int i = tid + j * 512;
        if (i < cntb) {
            v[j] = bd[i];
            rk[j] = atomicAdd(&hist[v[j] >> 17], 1);
        } else { v[j] = 0; rk[j] = -1; }
    }
    __syncthreads();
    if (tid < 64) {                      // wave 0: exclusive scan of hist
        int n = hist[tid], s = n;
        #pragma unroll
        for (int d = 1; d < 64; d <<= 1) {
            int t = __shfl_up(s, d, 64);
            if (tid >= d) s += t;
        }
        pre[tid] = s - n;
        int node = b * 64 + tid;
        if (node < N_NODES) {
            dinv[node] = rsqrtf((float)(n + 1));   // +1 self loop
            nstart[node] = b * BCAP + (s - n);
            nend[node]   = b * BCAP + s;
        }
    }
    __syncthreads();
    #pragma unroll
    for (int j = 0; j < 4; ++j) {
        if (rk[j] >= 0)
            buf[pre[v[j] >> 17] + rk[j]] = v[j] & 0x1FFFF;   // src only
    }
    __syncthreads();
    #pragma unroll
    for (int j = 0; j < 4; ++j) {
        int i = tid + j * 512;
        if (i < cntb) bd[i] = buf[i];    // coalesced writeback
    }
}

// ------- MFMA GEMM: hs[n][d] = (sum_k xs[n][k] * W[d][k]) * dinv[n], bf16 ----
__global__ __launch_bounds__(512) void gemm_kernel(const float* __restrict__ xs,
                                                   const float* __restrict__ W,
                                                   const float* __restrict__ dinv,
                                                   unsigned short* __restrict__ hs) {
    __shared__ bfrag8 wg[64 * 32];   // 32KB bf16 W
    const int tid = threadIdx.x;
    #pragma unroll
    for (int i = 0; i < 4; ++i) {
        int gi = tid + i * 512;              // 0..2047
        int d = gi >> 5, g = gi & 31;
        const float* src = W + d * 256 + g * 8;
        f32x4 f0 = *(const f32x4*)src;
        f32x4 f1 = *(const f32x4*)(src + 4);
        union { unsigned short us[8]; bfrag8 v; } p;
        p.us[0] = f2bf(f0.x); p.us[1] = f2bf(f0.y);
        p.us[2] = f2bf(f0.z); p.us[3] = f2bf(f0.w);
        p.us[4] = f2bf(f1.x); p.us[5] = f2bf(f1.y);
        p.us[6] = f2bf(f1.z); p.us[7] = f2bf(f1.w);
        wg[d * 32 + (g ^ (d & 7))] = p.v;
    }
    __syncthreads();

    const int lane = tid & 63, wv = tid >> 6;
    const int n0 = (blockIdx.x * 8 + wv) * 16;
    int arow = n0 + (lane & 15);
    if (arow >= N_NODES) arow = N_NODES - 1;          // clamp (loads only)
    const float* xrow = xs + (size_t)arow * DIN + (lane >> 4) * 8;

    f32x4 acc[4] = {{0.f, 0.f, 0.f, 0.f}, {0.f, 0.f, 0.f, 0.f},
                    {0.f, 0.f, 0.f, 0.f}, {0.f, 0.f, 0.f, 0.f}};
    const int swz = lane & 7;
    #pragma unroll
    for (int s = 0; s < 8; ++s) {
        f32x4 xa = *(const f32x4*)(xrow + s * 32);
        f32x4 xb = *(const f32x4*)(xrow + s * 32 + 4);
        union { unsigned short us[8]; bfrag8 v; } a;
        a.us[0] = f2bf(xa.x); a.us[1] = f2bf(xa.y);
        a.us[2] = f2bf(xa.z); a.us[3] = f2bf(xa.w);
        a.us[4] = f2bf(xb.x); a.us[5] = f2bf(xb.y);
        a.us[6] = f2bf(xb.z); a.us[7] = f2bf(xb.w);
        int g = s * 4 + (lane >> 4);
        #pragma unroll
        for (int t = 0; t < 4; ++t) {
            bfrag8 b = wg[(t * 16 + (lane & 15)) * 32 + (g ^ swz)];
            acc[t] = __builtin_amdgcn_mfma_f32_16x16x32_bf16(a.v, b, acc[t], 0, 0, 0);
        }
    }
    // C/D: col = lane&15, row = (lane>>4)*4 + r ; scale by dinv[row] on store
    #pragma unroll
    for (int t = 0; t < 4; ++t) {
        #pragma unroll
        for (int r = 0; r < 4; ++r) {
            int row = n0 + (lane >> 4) * 4 + r;
            if (row < N_NODES) {
                float dr = dinv[row];
                hs[(size_t)row * DOUT + t * 16 + (lane & 15)] = f2bf(acc[t][r] * dr);
            }
        }
    }
}

// -------- CSR aggregate: 4 nodes/wave, 16 lanes/node, uint2 (4 bf16)/lane ----
// (R12 measured-best shape: 8-deep unroll)
__global__ __launch_bounds__(256) void csr_agg_ln_kernel(
    const unsigned* __restrict__ csr, const int* __restrict__ nstart,
    const int* __restrict__ nend, const unsigned short* __restrict__ hs,
    const float* __restrict__ dinv, const float* __restrict__ bias,
    const float* __restrict__ gamma, const float* __restrict__ beta,
    float* __restrict__ out) {
    const int tid = threadIdx.x, lane = tid & 63, wv = tid >> 6;
    const int q = lane >> 4;          // which of the wave's 4 nodes
    const int fl = lane & 15;         // feature group (4 feats) within node
    const int node = (blockIdx.x * 4 + wv) * 4 + q;
    if (node >= N_NODES) return;
    const int c0 = nstart[node];
    const int deg = nend[node] - c0;
    const int cmax = deg > 0 ? deg - 1 : 0;

    // self loop (hs pre-scaled by dinv[src])
    uint2 sv = *(const uint2*)(hs + (size_t)node * DOUT + fl * 4);
    float a0 = bf2f((unsigned short)(sv.x & 0xFFFFu));
    float a1 = bf2f((unsigned short)(sv.x >> 16));
    float a2 = bf2f((unsigned short)(sv.y & 0xFFFFu));
    float a3 = bf2f((unsigned short)(sv.y >> 16));

    int maxd = deg;
    maxd = max(maxd, __shfl_xor(maxd, 16, 64));
    maxd = max(maxd, __shfl_xor(maxd, 32, 64));

    for (int j = 0; j < maxd; j += 8) {
        unsigned uu[8];
        #pragma unroll
        for (int k = 0; k < 8; ++k) {
            int jc = j + k; jc = jc < cmax ? jc : cmax;   // clamp, unconditional
            uu[k] = csr[c0 + jc];
        }
        uint2 hv[8];
        #pragma unroll
        for (int k = 0; k < 8; ++k) {
            unsigned src = uu[k];
            if (src > (unsigned)(N_NODES - 1)) src = N_NODES - 1;
            hv[k] = *(const uint2*)(hs + (size_t)src * DOUT + fl * 4);
        }
        #pragma unroll
        for (int k = 0; k < 8; ++k) {
            bool valid = (j + k) < deg;
            unsigned x = valid ? hv[k].x : 0u;   // cndmask, no branch
            unsigned y = valid ? hv[k].y : 0u;
            a0 += bf2f((unsigned short)(x & 0xFFFFu));
            a1 += bf2f((unsigned short)(x >> 16));
            a2 += bf2f((unsigned short)(y & 0xFFFFu));
            a3 += bf2f((unsigned short)(y >> 16));
        }
    }
    float di = dinv[node];
    float4 b4  = ((const float4*)bias)[fl];
    float4 g4  = ((const float4*)gamma)[fl];
    float4 be4 = ((const float4*)beta)[fl];
    a0 = a0 * di + b4.x;
    a1 = a1 * di + b4.y;
    a2 = a2 * di + b4.z;
    a3 = a3 * di + b4.w;
    // LayerNorm over 64 features = 16-lane group x 4 per lane
    float sum = (a0 + a1) + (a2 + a3);
    #pragma unroll
    for (int d = 1; d < 16; d <<= 1) sum += __shfl_xor(sum, d, 64);
    float mu = sum * (1.0f / 64.0f);
    float d0 = a0 - mu, d1 = a1 - mu, d2 = a2 - mu, d3 = a3 - mu;
    float vs = (d0 * d0 + d1 * d1) + (d2 * d2 + d3 * d3);
    #pragma unroll
    for (int d = 1; d < 16; d <<= 1) vs += __shfl_xor(vs, d, 64);
    float var = vs * (1.0f / 64.0f);
    float rinv = rsqrtf(var + LN_EPS);
    float4 ov;
    ov.x = d0 * rinv * g4.x + be4.x;
    ov.y = d1 * rinv * g4.y + be4.y;
    ov.z = d2 * rinv * g4.z + be4.z;
    ov.w = d3 * rinv * g4.w + be4.w;
    *(float4*)(out + (size_t)node * DOUT + fl * 4) = ov;
}

extern "C" void kernel_launch(void* const* d_in, const int* in_sizes, int n_in,
                              void* d_out, int out_size, void* d_ws, size_t ws_size,
                              hipStream_t stream) {
    const float* xs    = (const float*)d_in[0];
    const int*   ei    = (const int*)d_in[1];
    const float* W     = (const float*)d_in[2];
    const float* bias  = (const float*)d_in[3];
    const float* gamma = (const float*)d_in[4];
    const float* beta  = (const float*)d_in[5];
    float* out = (float*)d_out;

    char* base = (char*)d_ws;
    auto align_up = [](size_t x) { return (x + 255) & ~(size_t)255; };
    size_t o = 0;
    int* gcur   = (int*)(base + o);      o = align_up(o + (size_t)NB * 4);
    float* dinv = (float*)(base + o);    o = align_up(o + (size_t)N_NODES * 4);
    unsigned* bdata = (unsigned*)(base + o);           // becomes sorted csr
    o = align_up(o + (size_t)NB * BCAP * 4);
    unsigned short* hs = (unsigned short*)(base + o);
    o = align_up(o + (size_t)N_NODES * DOUT * 2);
    int* nstart = (int*)(base + o);      o = align_up(o + (size_t)N_NODES * 4);
    int* nend   = (int*)(base + o);      o = align_up(o + (size_t)N_NODES * 4);
    (void)ws_size; (void)in_sizes; (void)n_in; (void)out_size;

    zero_gcur_kernel<<<(NB + 255) / 256, 256, 0, stream>>>(gcur);
    partition_kernel<<<(N_EDGES + EPB - 1) / EPB, 512, 0, stream>>>(ei, gcur, bdata);
    sort_dinv_kernel<<<NB, 512, 0, stream>>>(bdata, gcur, dinv, nstart, nend);
    gemm_kernel<<<(N_NODES + 127) / 128, 512, 0, stream>>>(xs, W, dinv, hs);
    csr_agg_ln_kernel<<<(N_NODES + 15) / 16, 256, 0, stream>>>(
        bdata, nstart, nend, hs, dinv, bias, gamma, beta, out);
}